// Round 1
// baseline (469.317 us; speedup 1.0000x reference)
//
#include <hip/hip_runtime.h>

#define NPIX 4096
#define CCH  512
#define NGRP 32
#define BATCH 4

using bf16 = __bf16;
typedef __bf16 bf16x8 __attribute__((ext_vector_type(8)));
typedef __bf16 bf16x4 __attribute__((ext_vector_type(4)));
typedef float  f32x4  __attribute__((ext_vector_type(4)));

__device__ __forceinline__ f32x4 mfma16(bf16x8 a, bf16x8 b, f32x4 c) {
    return __builtin_amdgcn_mfma_f32_16x16x32_bf16(a, b, c, 0, 0, 0);
}

// ---------------- weights fp32 -> bf16 ----------------
__global__ __launch_bounds__(256) void cvt_w(const float* __restrict__ s, bf16* __restrict__ d) {
    int i = blockIdx.x * 256 + threadIdx.x;   // 65536 threads, 4 floats each = 262144
    float4 v = ((const float4*)s)[i];
    bf16x4 o;
    o[0] = (bf16)v.x; o[1] = (bf16)v.y; o[2] = (bf16)v.z; o[3] = (bf16)v.w;
    ((bf16x4*)d)[i] = o;
}

// ---------------- groupnorm stats: one block per (b,g) ----------------
__global__ __launch_bounds__(256) void gn_stats(const float* __restrict__ x, float2* __restrict__ stats) {
    int bg = blockIdx.x;                               // 0..127 ; group data is contiguous 65536 floats
    const float4* p = (const float4*)(x + (size_t)bg * 65536);
    float s = 0.f, ss = 0.f;
    for (int i = threadIdx.x; i < 16384; i += 256) {
        float4 v = p[i];
        s  += v.x + v.y + v.z + v.w;
        ss += v.x*v.x + v.y*v.y + v.z*v.z + v.w*v.w;
    }
    __shared__ float r1[256], r2[256];
    int t = threadIdx.x;
    r1[t] = s; r2[t] = ss;
    __syncthreads();
    for (int st = 128; st > 0; st >>= 1) {
        if (t < st) { r1[t] += r1[t+st]; r2[t] += r2[t+st]; }
        __syncthreads();
    }
    if (t == 0) {
        float mu  = r1[0] * (1.f/65536.f);
        float var = r2[0] * (1.f/65536.f) - mu*mu;
        stats[bg] = make_float2(mu, rsqrtf(var + 1e-6f));
    }
}

// ---------------- groupnorm apply + transpose -> hn_t[b][n][c] bf16 ----------------
__global__ __launch_bounds__(256) void gn_norm_t(const float* __restrict__ x,
                                                 const float2* __restrict__ stats,
                                                 const float* __restrict__ gw,
                                                 const float* __restrict__ gb,
                                                 bf16* __restrict__ hnt) {
    __shared__ float tile[64][65];                    // [c_local][n_local], +1 pad
    int n0 = blockIdx.x * 64, c0 = blockIdx.y * 64, b = blockIdx.z;
    int t = threadIdx.x;
    {
        int cr = t >> 4;                              // 0..15
        int nc = (t & 15) * 4;                        // 0..60
        #pragma unroll
        for (int rep = 0; rep < 4; ++rep) {
            int c = c0 + rep*16 + cr;
            float2 st = stats[b*NGRP + (c >> 4)];
            float w = gw[c], bb = gb[c];
            float4 v = *(const float4*)(x + ((size_t)b*CCH + c)*NPIX + n0 + nc);
            float* dst = &tile[rep*16 + cr][nc];
            dst[0] = (v.x - st.x)*st.y*w + bb;
            dst[1] = (v.y - st.x)*st.y*w + bb;
            dst[2] = (v.z - st.x)*st.y*w + bb;
            dst[3] = (v.w - st.x)*st.y*w + bb;
        }
    }
    __syncthreads();
    {
        int nr = t >> 2;                              // 0..63
        int cp = (t & 3) * 16;                        // 0,16,32,48
        bf16x8 o0, o1;
        #pragma unroll
        for (int j = 0; j < 8; ++j) {
            o0[j] = (bf16)tile[cp + j    ][nr];
            o1[j] = (bf16)tile[cp + 8 + j][nr];
        }
        bf16* dst = hnt + ((size_t)b*NPIX + n0 + nr)*CCH + c0 + cp;
        *(bf16x8*)dst       = o0;
        *((bf16x8*)dst + 1) = o1;
    }
}

// ---------------- 128x128-tile bf16 MFMA GEMM over [512 x 512] weights ----------------
// MODE 0: D[i][o] -> Yb[b][i][o] (spatial-major, Q/K), bias over col
// MODE 1: D[o][i] -> Yb[b][o][i] (channel-major, V), bias over row
// MODE 2: D[o][i] -> Yf[b][o][i] = acc + bias[o] + resid (proj, fp32 out)
template<int MODE>
__global__ __launch_bounds__(256, 2)
void gemm512(const bf16* __restrict__ W, const bf16* __restrict__ X,
             const float* __restrict__ bias, bf16* __restrict__ Yb,
             float* __restrict__ Yf, const float* __restrict__ resid) {
    __shared__ bf16 tX[128][40];
    __shared__ bf16 tW[128][40];
    int n0 = blockIdx.x * 128, o0 = blockIdx.y * 128, b = blockIdx.z;
    int t = threadIdx.x, lane = t & 63, w = t >> 6;
    int wm = (w >> 1) * 64, wn = (w & 1) * 64;
    int col = lane & 15, kq = (lane >> 4) * 8;
    f32x4 acc[4][4] = {};
    const bf16* gX = X + ((size_t)b*NPIX + n0) * CCH;
    const bf16* gW = W + (size_t)o0 * CCH;
    for (int k0 = 0; k0 < CCH; k0 += 32) {
        #pragma unroll
        for (int i = 0; i < 2; ++i) {
            int ch = t + i*256;                       // 0..511
            int r = ch >> 2, c = (ch & 3) * 8;
            *(bf16x8*)&tX[r][c] = *(const bf16x8*)(gX + (size_t)r*CCH + k0 + c);
            *(bf16x8*)&tW[r][c] = *(const bf16x8*)(gW + (size_t)r*CCH + k0 + c);
        }
        __syncthreads();
        bf16x8 fA[4], fB[4];
        #pragma unroll
        for (int i = 0; i < 4; ++i) {
            if (MODE == 0) {
                fA[i] = *(bf16x8*)&tX[wm + i*16 + col][kq];
                fB[i] = *(bf16x8*)&tW[wn + i*16 + col][kq];
            } else {
                fA[i] = *(bf16x8*)&tW[wm + i*16 + col][kq];
                fB[i] = *(bf16x8*)&tX[wn + i*16 + col][kq];
            }
        }
        #pragma unroll
        for (int i = 0; i < 4; ++i)
            #pragma unroll
            for (int j = 0; j < 4; ++j)
                acc[i][j] = mfma16(fA[i], fB[j], acc[i][j]);
        __syncthreads();
    }
    int row4 = (lane >> 4) * 4;
    #pragma unroll
    for (int i = 0; i < 4; ++i) {
        #pragma unroll
        for (int j = 0; j < 4; ++j) {
            #pragma unroll
            for (int r = 0; r < 4; ++r) {
                float vv = acc[i][j][r];
                int m = wm + i*16 + row4 + r;
                int n = wn + j*16 + col;
                if (MODE == 0) {
                    int sp = n0 + m, o = o0 + n;
                    Yb[((size_t)b*NPIX + sp)*CCH + o] = (bf16)(vv + bias[o]);
                } else if (MODE == 1) {
                    int o = o0 + m, sp = n0 + n;
                    Yb[((size_t)b*CCH + o)*NPIX + sp] = (bf16)(vv + bias[o]);
                } else {
                    int o = o0 + m, sp = n0 + n;
                    size_t idx = ((size_t)b*CCH + o)*NPIX + sp;
                    Yf[idx] = vv + bias[o] + resid[idx];
                }
            }
        }
    }
}

// ---------------- flash attention: 64 Q-rows/block, KVBLK=32 ----------------
// qt,kt: [B][N][C] bf16 ; v: [B][C][N] bf16 ; h2t out: [B][N][C] bf16
__global__ __launch_bounds__(256, 1)
void attn_flash(const bf16* __restrict__ qt, const bf16* __restrict__ kt,
                const bf16* __restrict__ v, bf16* __restrict__ h2t) {
    __shared__ bf16 Kt[32][520];       // [j][c]
    __shared__ bf16 Vt[512][40];       // [c][j]
    __shared__ bf16 Pl[4][16][40];     // per-wave P tile [i][j]
    int b = blockIdx.y;
    int t = threadIdx.x, lane = t & 63, w = t >> 6;
    int q0 = blockIdx.x * 64 + w * 16;
    int col = lane & 15, g = lane >> 4, kq = g * 8;

    // Q fragments: 16 rows x 512 c, held in registers
    bf16x8 qf[16];
    const bf16* qbase = qt + ((size_t)b*NPIX + q0 + col)*CCH + kq;
    #pragma unroll
    for (int kk = 0; kk < 16; ++kk) qf[kk] = *(const bf16x8*)(qbase + kk*32);

    f32x4 acc[32] = {};
    float mrun[4] = {-1e30f, -1e30f, -1e30f, -1e30f};
    float lrun[4] = {0.f, 0.f, 0.f, 0.f};
    const float cscale = 0.04419417382415922f;        // 512^-0.5

    for (int j0 = 0; j0 < NPIX; j0 += 32) {
        #pragma unroll
        for (int i = 0; i < 8; ++i) {                 // stage K: 32x512 bf16
            int ch = t + i*256;
            int r = ch >> 6, p = (ch & 63) * 8;
            *(bf16x8*)&Kt[r][p] = *(const bf16x8*)(kt + ((size_t)b*NPIX + j0 + r)*CCH + p);
        }
        #pragma unroll
        for (int i = 0; i < 8; ++i) {                 // stage V: 512x32 bf16
            int ch = t + i*256;
            int r = ch >> 2, p = (ch & 3) * 8;
            *(bf16x8*)&Vt[r][p] = *(const bf16x8*)(v + ((size_t)b*CCH + r)*NPIX + j0 + p);
        }
        __syncthreads();

        // S = Q K^T  (two 16-col halves, 2-way split-K for ILP)
        f32x4 s0a = {}, s0b = {}, s1a = {}, s1b = {};
        #pragma unroll
        for (int kk = 0; kk < 16; kk += 2) {
            s0a = mfma16(qf[kk],   *(bf16x8*)&Kt[col     ][kk*32 + kq],     s0a);
            s1a = mfma16(qf[kk],   *(bf16x8*)&Kt[col + 16][kk*32 + kq],     s1a);
            s0b = mfma16(qf[kk+1], *(bf16x8*)&Kt[col     ][(kk+1)*32 + kq], s0b);
            s1b = mfma16(qf[kk+1], *(bf16x8*)&Kt[col + 16][(kk+1)*32 + kq], s1b);
        }
        f32x4 s0 = (s0a + s0b) * cscale;
        f32x4 s1 = (s1a + s1b) * cscale;

        // online softmax (rows (g*4+r), cols = col + 16*jh)
        float tmax[4];
        int grow = 0;
        #pragma unroll
        for (int r = 0; r < 4; ++r) {
            float tm = fmaxf(s0[r], s1[r]);
            #pragma unroll
            for (int off = 1; off < 16; off <<= 1) tm = fmaxf(tm, __shfl_xor(tm, off));
            tmax[r] = tm;
            grow |= (tm > mrun[r] + 8.f) ? 1 : 0;
        }
        if (__any(grow)) {                            // defer-max rescale (THR=8)
            #pragma unroll
            for (int r = 0; r < 4; ++r) {
                float mnew  = fmaxf(mrun[r], tmax[r]);
                float alpha = __expf(mrun[r] - mnew);
                lrun[r] *= alpha;
                mrun[r] = mnew;
                #pragma unroll
                for (int cf = 0; cf < 32; ++cf) acc[cf][r] *= alpha;
            }
        }
        #pragma unroll
        for (int r = 0; r < 4; ++r) {
            float p0 = __expf(s0[r] - mrun[r]);
            float p1 = __expf(s1[r] - mrun[r]);
            float rs = p0 + p1;
            #pragma unroll
            for (int off = 1; off < 16; off <<= 1) rs += __shfl_xor(rs, off);
            lrun[r] += rs;
            Pl[w][g*4 + r][col]      = (bf16)p0;
            Pl[w][g*4 + r][col + 16] = (bf16)p1;
        }

        // PV: O[i][c] += P(16x32) * V(32x512)
        bf16x8 pa = *(bf16x8*)&Pl[w][col][kq];
        #pragma unroll
        for (int cf = 0; cf < 32; ++cf) {
            acc[cf] = mfma16(pa, *(bf16x8*)&Vt[cf*16 + col][kq], acc[cf]);
        }
        __syncthreads();
    }

    float rl[4];
    #pragma unroll
    for (int r = 0; r < 4; ++r) rl[r] = 1.f / lrun[r];
    #pragma unroll
    for (int cf = 0; cf < 32; ++cf) {
        #pragma unroll
        for (int r = 0; r < 4; ++r) {
            h2t[((size_t)b*NPIX + q0 + g*4 + r)*CCH + cf*16 + col] = (bf16)(acc[cf][r] * rl[r]);
        }
    }
}

extern "C" void kernel_launch(void* const* d_in, const int* in_sizes, int n_in,
                              void* d_out, int out_size, void* d_ws, size_t ws_size,
                              hipStream_t stream) {
    (void)in_sizes; (void)n_in; (void)out_size; (void)ws_size;
    const float* x   = (const float*)d_in[0];
    const float* gnw = (const float*)d_in[1];
    const float* gnb = (const float*)d_in[2];
    const float* wq  = (const float*)d_in[3];
    const float* bq  = (const float*)d_in[4];
    const float* wk  = (const float*)d_in[5];
    const float* bk  = (const float*)d_in[6];
    const float* wv  = (const float*)d_in[7];
    const float* bv  = (const float*)d_in[8];
    const float* wp  = (const float*)d_in[9];
    const float* bp  = (const float*)d_in[10];

    char* ws = (char*)d_ws;
    bf16* wqb = (bf16*)ws;                    // 4 x 512*512 bf16
    bf16* wkb = wqb + 262144;
    bf16* wvb = wkb + 262144;
    bf16* wpb = wvb + 262144;
    float2* stats = (float2*)(ws + 4*524288); // 128 float2
    bf16* hnt = (bf16*)(ws + 4*524288 + 4096);
    bf16* qt  = hnt + (size_t)BATCH*NPIX*CCH;
    bf16* kt  = qt  + (size_t)BATCH*NPIX*CCH;
    bf16* vch = kt  + (size_t)BATCH*NPIX*CCH;
    bf16* h2t = vch + (size_t)BATCH*NPIX*CCH;

    cvt_w<<<256, 256, 0, stream>>>(wq, wqb);
    cvt_w<<<256, 256, 0, stream>>>(wk, wkb);
    cvt_w<<<256, 256, 0, stream>>>(wv, wvb);
    cvt_w<<<256, 256, 0, stream>>>(wp, wpb);

    gn_stats<<<BATCH*NGRP, 256, 0, stream>>>(x, stats);
    gn_norm_t<<<dim3(NPIX/64, CCH/64, BATCH), 256, 0, stream>>>(x, stats, gnw, gnb, hnt);

    dim3 ggrid(NPIX/128, CCH/128, BATCH);
    gemm512<0><<<ggrid, 256, 0, stream>>>(wqb, hnt, bq, qt,  nullptr, nullptr);
    gemm512<0><<<ggrid, 256, 0, stream>>>(wkb, hnt, bk, kt,  nullptr, nullptr);
    gemm512<1><<<ggrid, 256, 0, stream>>>(wvb, hnt, bv, vch, nullptr, nullptr);

    attn_flash<<<dim3(NPIX/64, BATCH), 256, 0, stream>>>(qt, kt, vch, h2t);

    gemm512<2><<<ggrid, 256, 0, stream>>>(wpb, h2t, bp, nullptr, (float*)d_out, x);
}